// Round 2
// 219.826 us; speedup vs baseline: 1.0298x; 1.0298x over previous
//
#include <hip/hip_runtime.h>
#include <hip/hip_fp16.h>

// SpatialTransform: fused meshgrid + flow displacement + bilinear grid_sample
// (align_corners=True, padding_mode='border'). B=16, C=4, H=W=512, fp32.
// d_out = [ sample_grid (B*H*W*2 floats) | warped (B*C*H*W floats) ]
//
// R5 = R4 with compile fix: __builtin_nontemporal_* requires plain vector
// types, not HIP_vector_type (float4). Use ext_vector_type typedefs.
// R4 rationale (from R3 @ 226us): pass-2 counters showed latency-bound
// (VALUBusy 9.5%, HBM 29%, FETCH near-ideal 55.7MB). Changes:
//  1. 4 px/thread both passes: 8 independent gather loads in flight (was 4),
//     VMEM instrs/pixel 5->4, waves halved. MLP x2 for the gather chain.
//  2. Non-temporal stores (grid, warped) + nt loads (flow, img): keep the
//     100MB output stream from evicting the fp16 copies out of per-XCD L2.
//  3. Pass 1 uses the SAME XCD slab swizzle; pass 2 walks slabs in REVERSE
//     (i^511) so each XCD starts on the slab it wrote last (L2-hot).
// Dual fp16 HWC copies kept from R3: any (x0,x0+1) pair = one 16B load.

#define HW    512
#define BATCH 16
#define CH     4
#define HWHW  (HW * HW)

typedef float fvec4 __attribute__((ext_vector_type(4)));

union H4 { uint2 u; __half2 h[2]; };   // one pixel: 4 channels fp16
union Q  { uint4 u; __half2 h[4]; };   // one slot: 2 pixels x 4 channels fp16

// ---------------------------------------------------------------------------
// Pass 1: [B,C,H,W] fp32 -> two fp16 HWC copies. 4 pixels/thread, 2 rows/block.
// copyA slot p = pixel p. copyB slot p = pixel p+1 (slot 511 of row = px 511).
// Block->row mapping matches pass 2's slab swizzle (forward order).
__global__ __launch_bounds__(256) void transpose_fp16_dual(
    const fvec4* __restrict__ img4,
    uint2* __restrict__ copyA,
    uint2* __restrict__ copyB)
{
    // 4096 blocks; xcd = j&7 owns contiguous 256-row slabs.
    const int j    = blockIdx.x;
    const int xcd  = j & 7;
    const int i    = j >> 3;                        // 0..511 (forward)
    const int slab = ((i >> 7) << 3) | xcd;         // 0..31
    const int rp   = (slab << 7) | (i & 127);       // row-pair 0..4095
    const int r    = (rp << 1) | ((int)threadIdx.x >> 7);  // global row 0..8191
    const int lane = (int)threadIdx.x & 127;
    const int b    = r >> 9;
    const int y    = r & (HW - 1);
    const int x    = lane << 2;                     // 0,4,...,508

    const int p = r * HW + x;                       // global pixel index
    const int q = (y * HW + x) >> 2;                // quad index within plane

    const fvec4* ib = img4 + (size_t)b * CH * (HWHW / 4) + q;
    const fvec4 c0 = __builtin_nontemporal_load(ib + 0 * (HWHW / 4));
    const fvec4 c1 = __builtin_nontemporal_load(ib + 1 * (HWHW / 4));
    const fvec4 c2 = __builtin_nontemporal_load(ib + 2 * (HWHW / 4));
    const fvec4 c3 = __builtin_nontemporal_load(ib + 3 * (HWHW / 4));

    H4 v0, v1, v2, v3;                              // pixels p..p+3
    v0.h[0] = __floats2half2_rn(c0.x, c1.x); v0.h[1] = __floats2half2_rn(c2.x, c3.x);
    v1.h[0] = __floats2half2_rn(c0.y, c1.y); v1.h[1] = __floats2half2_rn(c2.y, c3.y);
    v2.h[0] = __floats2half2_rn(c0.z, c1.z); v2.h[1] = __floats2half2_rn(c2.z, c3.z);
    v3.h[0] = __floats2half2_rn(c0.w, c1.w); v3.h[1] = __floats2half2_rn(c2.w, c3.w);

    // copyA: two aligned 16B stores (pixels p..p+3)
    Q a0; a0.u.x = v0.u.x; a0.u.y = v0.u.y; a0.u.z = v1.u.x; a0.u.w = v1.u.y;
    Q a1; a1.u.x = v2.u.x; a1.u.y = v2.u.y; a1.u.z = v3.u.x; a1.u.w = v3.u.y;
    ((uint4*)copyA)[(p >> 1) + 0] = a0.u;
    ((uint4*)copyA)[(p >> 1) + 1] = a1.u;

    // copyB: slot p-1..p+2 <- pixels p..p+3 (B[s] = px s+1)
    Q bm; bm.u.x = v1.u.x; bm.u.y = v1.u.y; bm.u.z = v2.u.x; bm.u.w = v2.u.y;
    ((uint4*)copyB)[p >> 1] = bm.u;                 // slots p,p+1 <- px p+1,p+2
    if (x != 0)       copyB[p - 1] = v0.u;          // slot p-1 <- px p
    copyB[p + 2] = v3.u;                            // slot p+2 <- px p+3
    if (x == HW - 4)  copyB[p + 3] = v3.u;          // slot 511 replicates px 511
}

// ---------------------------------------------------------------------------
// Bilinear addressing into the dual-copy fp16 image.
__device__ __forceinline__ void addr2(const uint4* __restrict__ A,
                                      const uint4* __restrict__ B,
                                      float gx, float gy,
                                      const uint4** p0, const uint4** p1,
                                      float* wx, float* wy)
{
    float xs = fminf(fmaxf((gx + 1.0f) * 0.5f * 511.0f, 0.0f), 511.0f);
    float ys = fminf(fmaxf((gy + 1.0f) * 0.5f * 511.0f, 0.0f), 511.0f);
    const float x0f = floorf(xs);
    const float y0f = floorf(ys);
    *wx = xs - x0f;
    *wy = ys - y0f;
    const int x0 = (int)x0f;
    const int y0 = (int)y0f;
    const int y1 = min(y0 + 1, HW - 1);
    const uint4* base = (x0 & 1) ? B : A;
    const int slot = x0 >> 1;
    *p0 = base + y0 * (HW / 2) + slot;
    *p1 = base + y1 * (HW / 2) + slot;
}

__device__ __forceinline__ float4 blend(Q r0, Q r1, float wx, float wy)
{
    const float w00 = (1.0f - wx) * (1.0f - wy);
    const float w01 = wx * (1.0f - wy);
    const float w10 = (1.0f - wx) * wy;
    const float w11 = wx * wy;
    float4 o;
    o.x = w00 * __low2float (r0.h[0]) + w01 * __low2float (r0.h[2])
        + w10 * __low2float (r1.h[0]) + w11 * __low2float (r1.h[2]);
    o.y = w00 * __high2float(r0.h[0]) + w01 * __high2float(r0.h[2])
        + w10 * __high2float(r1.h[0]) + w11 * __high2float(r1.h[2]);
    o.z = w00 * __low2float (r0.h[1]) + w01 * __low2float (r0.h[3])
        + w10 * __low2float (r1.h[1]) + w11 * __low2float (r1.h[3]);
    o.w = w00 * __high2float(r0.h[1]) + w01 * __high2float(r0.h[3])
        + w10 * __high2float(r1.h[1]) + w11 * __high2float(r1.h[3]);
    return o;
}

// Pass 2: 4 px/thread, 2 rows/block, slab-swizzled to XCDs in REVERSE order
// (starts where pass 1 finished -> L2-hot). 8 gather loads in flight.
__global__ __launch_bounds__(256) void spatial_transform_fp16(
    const uint4* __restrict__ copyA,
    const uint4* __restrict__ copyB,
    const fvec4* __restrict__ flow4, // [B*H*W/2]: (fh0,fw0,fh1,fw1)
    fvec4* __restrict__ grid4,       // [B*H*W/2]: (gx0,gy0,gx1,gy1)
    float* __restrict__ warped)      // [B,C,H,W]
{
    const int j    = blockIdx.x;                    // 0..4095
    const int xcd  = j & 7;
    const int i    = (j >> 3) ^ 511;                // REVERSED intra-XCD order
    const int slab = ((i >> 7) << 3) | xcd;         // 0..31
    const int rp   = (slab << 7) | (i & 127);       // row-pair 0..4095
    const int r    = (rp << 1) | ((int)threadIdx.x >> 7);  // global row
    const int lane = (int)threadIdx.x & 127;
    const int b    = r >> 9;
    const int y    = r & (HW - 1);
    const int x    = lane << 2;

    const int p = r * HW + x;                       // global pixel index
    const fvec4 f01 = __builtin_nontemporal_load(flow4 + (p >> 1) + 0);
    const fvec4 f23 = __builtin_nontemporal_load(flow4 + (p >> 1) + 1);

    const float scale = 2.0f / 511.0f;
    const float by = fmaf((float)y, scale, -1.0f);
    const float gy0 = by + f01.x;
    const float gx0 = fmaf((float)(x + 0), scale, -1.0f) + f01.y;
    const float gy1 = by + f01.z;
    const float gx1 = fmaf((float)(x + 1), scale, -1.0f) + f01.w;
    const float gy2 = by + f23.x;
    const float gx2 = fmaf((float)(x + 2), scale, -1.0f) + f23.y;
    const float gy3 = by + f23.z;
    const float gx3 = fmaf((float)(x + 3), scale, -1.0f) + f23.w;

    const uint4* A  = copyA + (size_t)b * (HW * (HW / 2));
    const uint4* Bc = copyB + (size_t)b * (HW * (HW / 2));

    // Phase A: all addresses
    const uint4 *p00, *p01, *p10, *p11, *p20, *p21, *p30, *p31;
    float wx0, wy0, wx1, wy1, wx2, wy2, wx3, wy3;
    addr2(A, Bc, gx0, gy0, &p00, &p01, &wx0, &wy0);
    addr2(A, Bc, gx1, gy1, &p10, &p11, &wx1, &wy1);
    addr2(A, Bc, gx2, gy2, &p20, &p21, &wx2, &wy2);
    addr2(A, Bc, gx3, gy3, &p30, &p31, &wx3, &wy3);

    // Phase B: 8 independent gathers in flight
    Q q00, q01, q10, q11, q20, q21, q30, q31;
    q00.u = *p00; q01.u = *p01;
    q10.u = *p10; q11.u = *p11;
    q20.u = *p20; q21.u = *p21;
    q30.u = *p30; q31.u = *p31;

    // grid store overlaps the gather latency
    fvec4 g01; g01.x = gx0; g01.y = gy0; g01.z = gx1; g01.w = gy1;
    fvec4 g23; g23.x = gx2; g23.y = gy2; g23.z = gx3; g23.w = gy3;
    __builtin_nontemporal_store(g01, grid4 + (p >> 1) + 0);
    __builtin_nontemporal_store(g23, grid4 + (p >> 1) + 1);

    // Phase C: blend + transposed channel stores
    const float4 s0 = blend(q00, q01, wx0, wy0);
    const float4 s1 = blend(q10, q11, wx1, wy1);
    const float4 s2 = blend(q20, q21, wx2, wy2);
    const float4 s3 = blend(q30, q31, wx3, wy3);

    fvec4* wb = (fvec4*)(warped + (size_t)b * CH * HWHW + y * HW + x);
    fvec4 o0; o0.x = s0.x; o0.y = s1.x; o0.z = s2.x; o0.w = s3.x;
    fvec4 o1; o1.x = s0.y; o1.y = s1.y; o1.z = s2.y; o1.w = s3.y;
    fvec4 o2; o2.x = s0.z; o2.y = s1.z; o2.z = s2.z; o2.w = s3.z;
    fvec4 o3; o3.x = s0.w; o3.y = s1.w; o3.z = s2.w; o3.w = s3.w;
    __builtin_nontemporal_store(o0, wb + 0 * (HWHW / 4));
    __builtin_nontemporal_store(o1, wb + 1 * (HWHW / 4));
    __builtin_nontemporal_store(o2, wb + 2 * (HWHW / 4));
    __builtin_nontemporal_store(o3, wb + 3 * (HWHW / 4));
}

// ---------------------------------------------------------------------------
// Fallback (R0 path) if workspace is too small.
__global__ __launch_bounds__(256) void spatial_transform_chw(
    const float*  __restrict__ img,
    const float2* __restrict__ flow,
    float2*       __restrict__ grid_out,
    float*        __restrict__ warped)
{
    const int tid = blockIdx.x * blockDim.x + threadIdx.x;
    const int x = tid & (HW - 1);
    const int y = (tid >> 9) & (HW - 1);
    const int b = tid >> 18;

    const float2 f = flow[tid];
    const float scale = 2.0f / 511.0f;
    const float gy = fmaf((float)y, scale, -1.0f) + f.x;
    const float gx = fmaf((float)x, scale, -1.0f) + f.y;
    grid_out[tid] = make_float2(gx, gy);

    float xs = fminf(fmaxf((gx + 1.0f) * 0.5f * 511.0f, 0.0f), 511.0f);
    float ys = fminf(fmaxf((gy + 1.0f) * 0.5f * 511.0f, 0.0f), 511.0f);
    const float x0f = floorf(xs), y0f = floorf(ys);
    const float wx = xs - x0f, wy = ys - y0f;
    const int x0 = (int)x0f, y0 = (int)y0f;
    const int x1 = min(x0 + 1, HW - 1), y1 = min(y0 + 1, HW - 1);
    const float w00 = (1.0f - wx) * (1.0f - wy), w01 = wx * (1.0f - wy);
    const float w10 = (1.0f - wx) * wy,          w11 = wx * wy;
    const int o00 = y0 * HW + x0, o01 = y0 * HW + x1;
    const int o10 = y1 * HW + x0, o11 = y1 * HW + x1;
    const float* ib = img    + (size_t)b * CH * HWHW;
    float*       wb = warped + (size_t)b * CH * HWHW + y * HW + x;
#pragma unroll
    for (int c = 0; c < CH; ++c) {
        const float* pc = ib + c * HWHW;
        wb[c * HWHW] = pc[o00] * w00 + pc[o01] * w01 + pc[o10] * w10 + pc[o11] * w11;
    }
}

extern "C" void kernel_launch(void* const* d_in, const int* in_sizes, int n_in,
                              void* d_out, int out_size, void* d_ws, size_t ws_size,
                              hipStream_t stream) {
    const float* img  = (const float*)d_in[0];
    const void*  flow = d_in[1];

    float* grid_out = (float*)d_out;                                  // B*H*W*2 floats
    float* warped   = (float*)d_out + (size_t)BATCH * HWHW * 2;       // B*C*H*W floats

    const int n_px = BATCH * HWHW;                       // 4,194,304 pixels
    const size_t copy_bytes = (size_t)n_px * 8;          // 32 MiB per fp16 copy
    const size_t need = 2 * copy_bytes;                  // 64 MiB

    if (ws_size >= need) {
        uint2* copyA = (uint2*)d_ws;
        uint2* copyB = (uint2*)((char*)d_ws + copy_bytes);
        transpose_fp16_dual<<<(n_px / 4) / 256, 256, 0, stream>>>(
            (const fvec4*)img, copyA, copyB);
        spatial_transform_fp16<<<(n_px / 4) / 256, 256, 0, stream>>>(
            (const uint4*)copyA, (const uint4*)copyB,
            (const fvec4*)flow, (fvec4*)grid_out, warped);
    } else {
        spatial_transform_chw<<<n_px / 256, 256, 0, stream>>>(
            img, (const float2*)flow, (float2*)grid_out, warped);
    }
}